// Round 5
// baseline (91.044 us; speedup 1.0000x reference)
//
#include <hip/hip_runtime.h>
#include <math.h>

// DigitCaps2: B=128, C=1024 in_caps, I=16 in_dim, N=16 num_caps, D=16 dim_caps
#define NB 128
#define NC 1024
#define NN 16
#define ND 16
#define NI 16
#define COEF 0.25f

typedef __attribute__((ext_vector_type(8))) short short8;
typedef __attribute__((ext_vector_type(4))) float f32x4;
typedef unsigned short ushort_t;

__device__ __forceinline__ unsigned short f2bf(float f) {
  unsigned int u = __builtin_bit_cast(unsigned int, f);
  u += 0x7fffu + ((u >> 16) & 1u);
  return (unsigned short)(u >> 16);
}

// K1: convert x (262144 groups of 8) and W (524288 groups) to bf16.
__global__ __launch_bounds__(256) void k_prep(const float4* __restrict__ x,
                                              const float4* __restrict__ W,
                                              ushort_t* __restrict__ xb,
                                              ushort_t* __restrict__ Wb) {
  int id = blockIdx.x * 256 + threadIdx.x;
  const float4* src;
  ushort_t* dst;
  int k;
  if (id < 262144) { src = x; dst = xb; k = id; }
  else { src = W; dst = Wb; k = id - 262144; }
  float4 a = src[2 * k], b = src[2 * k + 1];
  short8 o;
  o[0] = (short)f2bf(a.x); o[1] = (short)f2bf(a.y);
  o[2] = (short)f2bf(a.z); o[3] = (short)f2bf(a.w);
  o[4] = (short)f2bf(b.x); o[5] = (short)f2bf(b.y);
  o[6] = (short)f2bf(b.z); o[7] = (short)f2bf(b.w);
  *(short8*)(dst + (size_t)k * 8) = o;
}

// K2: usum half-partials. block = n*16 + bt*2 + h (256 blocks, 16 waves).
// wave w owns c in [h*512 + w*32, +32) -> 16 K=32 steps as 2 independent chains.
// LDS-reduce 16 waves -> usum2[h][n][b][d].
__global__ __launch_bounds__(1024) void k_usum(const ushort_t* __restrict__ xb,
                                               const ushort_t* __restrict__ Wb,
                                               float* __restrict__ usum2) {
  __shared__ f32x4 red[16][64];  // 16 KB
  int bx = blockIdx.x;
  int n = bx >> 4, bt = (bx >> 1) & 7, h = bx & 1;
  int w = threadIdx.x >> 6, l = threadIdx.x & 63;
  int q = l >> 4, b16 = l & 15;
  int c0 = h * 512 + w * 32;
  const ushort_t* ap0 = Wb + (((size_t)(n * NC + c0 + (q >> 1)) * ND + b16) * NI) + (q & 1) * 8;
  const ushort_t* bp0 = xb + (size_t)(bt * 16 + b16) * (NC * NI) + (c0 + (q >> 1)) * NI + (q & 1) * 8;
  const ushort_t* ap1 = ap0 + 16 * ND * NI;  // +16 c
  const ushort_t* bp1 = bp0 + 16 * NI;
  f32x4 acc0 = {0.f, 0.f, 0.f, 0.f};
  f32x4 acc1 = {0.f, 0.f, 0.f, 0.f};
#pragma unroll
  for (int s = 0; s < 8; ++s) {
    short8 a0 = *(const short8*)ap0;
    short8 b0 = *(const short8*)bp0;
    short8 a1 = *(const short8*)ap1;
    short8 b1 = *(const short8*)bp1;
    acc0 = __builtin_amdgcn_mfma_f32_16x16x32_bf16(a0, b0, acc0, 0, 0, 0);
    acc1 = __builtin_amdgcn_mfma_f32_16x16x32_bf16(a1, b1, acc1, 0, 0, 0);
    ap0 += 2 * ND * NI; bp0 += 2 * NI;
    ap1 += 2 * ND * NI; bp1 += 2 * NI;
  }
  red[w][l] = acc0 + acc1;
  __syncthreads();
  if (threadIdx.x < 64) {
    f32x4 t = red[0][l];
#pragma unroll
    for (int k = 1; k < 16; ++k) t += red[k][l];
    // lane l = (q,b16) holds rows d=q*4+r, col b=b16
    *(f32x4*)(usum2 + (((size_t)h * NN + n) * NB + bt * 16 + b16) * ND + q * 4) = t;
  }
}

// K3: fused scores + softmax + weighted-sum partials.
// block = bt*32 + cc (256 blocks x 1024 threads); wave = n.
__global__ __launch_bounds__(1024) void k_bc(const ushort_t* __restrict__ xb,
                                             const ushort_t* __restrict__ Wb,
                                             const float* __restrict__ usum2,
                                             const float* __restrict__ Bbias,
                                             float* __restrict__ part) {
  __shared__ float scl[NN * 32 * 16];  // [n][c][b16], 32 KB
  int bx = blockIdx.x;
  int bt = bx >> 5, cc = bx & 31;
  int n = threadIdx.x >> 6, l = threadIdx.x & 63;
  int q = l >> 4, b16 = l & 15;
  int c0 = cc * 32;

  // phase 0: usum = half0 + half1
  f32x4 us = *(const f32x4*)(usum2 + (((size_t)0 * NN + n) * NB + bt * 16 + b16) * ND + q * 4) +
             *(const f32x4*)(usum2 + (((size_t)1 * NN + n) * NB + bt * 16 + b16) * ND + q * 4);

  // phase 1: scores[n][c][b] = COEF * sum_d usum[b,n,d] * u_hat[b,n,c,d]
  const ushort_t* ap = Wb + (((size_t)(n * NC + c0) * ND + b16) * NI) + (q & 1) * 8;
  const ushort_t* bp = xb + (size_t)(bt * 16 + b16) * (NC * NI) + c0 * NI + (q & 1) * 8;
  {
    const ushort_t* a2 = ap;
    const ushort_t* b2 = bp;
    for (int c = 0; c < 32; ++c) {
      short8 av = {0, 0, 0, 0, 0, 0, 0, 0};
      short8 bv = {0, 0, 0, 0, 0, 0, 0, 0};
      if (q < 2) {
        av = *(const short8*)a2;
        bv = *(const short8*)b2;
      }
      f32x4 z = {0.f, 0.f, 0.f, 0.f};
      f32x4 d = __builtin_amdgcn_mfma_f32_16x16x32_bf16(av, bv, z, 0, 0, 0);
      float v = us[0] * d[0] + us[1] * d[1] + us[2] * d[2] + us[3] * d[3];
      v += __shfl_xor(v, 16);
      v += __shfl_xor(v, 32);
      if (q == 0) scl[(n * 32 + c) * 16 + b16] = COEF * v;
      a2 += ND * NI;
      b2 += NI;
    }
  }
  __syncthreads();

  // phase 2: softmax over n + bias, in place (thread owns (c,b) column)
  if (threadIdx.x < 512) {
    int c = threadIdx.x >> 4, b = threadIdx.x & 15;
    float v[NN];
    float m = -1e30f;
#pragma unroll
    for (int k = 0; k < NN; ++k) {
      v[k] = scl[(k * 32 + c) * 16 + b];
      m = fmaxf(m, v[k]);
    }
    float sum = 0.f;
#pragma unroll
    for (int k = 0; k < NN; ++k) {
      v[k] = expf(v[k] - m);
      sum += v[k];
    }
    float inv = 1.0f / sum;
#pragma unroll
    for (int k = 0; k < NN; ++k) {
      scl[(k * 32 + c) * 16 + b] = v[k] * inv + Bbias[k * NC + c0 + c];
    }
  }
  __syncthreads();

  // phase 3: s partials — recompute per-c d-tile (L1-hot addresses), f32 scale-accumulate
  f32x4 acc = {0.f, 0.f, 0.f, 0.f};
  for (int c = 0; c < 32; ++c) {
    short8 av = {0, 0, 0, 0, 0, 0, 0, 0};
    short8 bv = {0, 0, 0, 0, 0, 0, 0, 0};
    if (q < 2) {
      av = *(const short8*)ap;
      bv = *(const short8*)bp;
    }
    f32x4 z = {0.f, 0.f, 0.f, 0.f};
    f32x4 d = __builtin_amdgcn_mfma_f32_16x16x32_bf16(av, bv, z, 0, 0, 0);
    float cf = scl[(n * 32 + c) * 16 + b16];
    acc[0] = fmaf(cf, d[0], acc[0]);
    acc[1] = fmaf(cf, d[1], acc[1]);
    acc[2] = fmaf(cf, d[2], acc[2]);
    acc[3] = fmaf(cf, d[3], acc[3]);
    ap += ND * NI;
    bp += NI;
  }
  *(f32x4*)(part + ((size_t)((n * 8 + bt) * 32 + cc)) * 256 + b16 * 16 + q * 4) = acc;
}

// K4: reduce s partials over cc + squash -> out[b][n][d]. thread = (b,n,dq).
__global__ __launch_bounds__(256) void k_fin(const float* __restrict__ part,
                                             float* __restrict__ out) {
  int id = blockIdx.x * 256 + threadIdx.x;  // 8192 = b*64 + n*4 + dq
  int dq = id & 3, n = (id >> 2) & 15, b = id >> 6;
  int bt = b >> 4, b16 = b & 15;
  f32x4 sv = {0.f, 0.f, 0.f, 0.f};
  const float* pp = part + ((size_t)((n * 8 + bt) * 32)) * 256 + b16 * 16 + dq * 4;
  for (int kc = 0; kc < 32; ++kc) {
    f32x4 p = *(const f32x4*)pp;
    sv += p;
    pp += 256;
  }
  float sq = sv[0] * sv[0] + sv[1] * sv[1] + sv[2] * sv[2] + sv[3] * sv[3];
  sq += __shfl_xor(sq, 1);
  sq += __shfl_xor(sq, 2);
  float norm = sqrtf(sq);
  float scale = (1.0f - expf(-norm)) / sqrtf(sq + 1e-8f);
  f32x4 o = {sv[0] * scale, sv[1] * scale, sv[2] * scale, sv[3] * scale};
  *(f32x4*)(out + (size_t)id * 4) = o;
}

extern "C" void kernel_launch(void* const* d_in, const int* in_sizes, int n_in,
                              void* d_out, int out_size, void* d_ws, size_t ws_size,
                              hipStream_t stream) {
  const float* x = (const float*)d_in[0];   // [128][1024][16]
  const float* W = (const float*)d_in[1];   // [1][16][1024][16][16]
  const float* Bb = (const float*)d_in[2];  // [16][1][1024]
  float* out = (float*)d_out;               // [128][16][16]
  float* ws = (float*)d_ws;

  // ws layout (float units): ~17 MB total
  ushort_t* xb = (ushort_t*)ws;              // 2,097,152 bf16 = 1,048,576 f
  ushort_t* Wb = (ushort_t*)(ws + 1048576);  // 4,194,304 bf16 = 2,097,152 f
  float* part = ws + 1048576 + 2097152;      // [16][8][32][256] = 1,048,576 f
  float* usum2 = part + 1048576;             // [2][16][128][16] = 65,536 f

  hipLaunchKernelGGL(k_prep, dim3(3072), dim3(256), 0, stream,
                     (const float4*)x, (const float4*)W, xb, Wb);
  hipLaunchKernelGGL(k_usum, dim3(256), dim3(1024), 0, stream, xb, Wb, usum2);
  hipLaunchKernelGGL(k_bc, dim3(256), dim3(1024), 0, stream, xb, Wb, usum2, Bb, part);
  hipLaunchKernelGGL(k_fin, dim3(32), dim3(256), 0, stream, part, out);
}

// Round 6
// 70.615 us; speedup vs baseline: 1.2893x; 1.2893x over previous
//
#include <hip/hip_runtime.h>
#include <math.h>

// DigitCaps2: B=128, C=1024 in_caps, I=16 in_dim, N=16 num_caps, D=16 dim_caps
#define NB 128
#define NC 1024
#define NN 16
#define ND 16
#define NI 16
#define COEF 0.25f

typedef __attribute__((ext_vector_type(8))) short short8;
typedef __attribute__((ext_vector_type(4))) float f32x4;
typedef unsigned short ushort_t;

__device__ __forceinline__ unsigned short f2bf(float f) {
  unsigned int u = __builtin_bit_cast(unsigned int, f);
  u += 0x7fffu + ((u >> 16) & 1u);
  return (unsigned short)(u >> 16);
}

// K1: convert x (262144 groups of 8) and W (524288 groups) to bf16.
__global__ __launch_bounds__(256) void k_prep(const float4* __restrict__ x,
                                              const float4* __restrict__ W,
                                              ushort_t* __restrict__ xb,
                                              ushort_t* __restrict__ Wb) {
  int id = blockIdx.x * 256 + threadIdx.x;
  const float4* src;
  ushort_t* dst;
  int k;
  if (id < 262144) { src = x; dst = xb; k = id; }
  else { src = W; dst = Wb; k = id - 262144; }
  float4 a = src[2 * k], b = src[2 * k + 1];
  short8 o;
  o[0] = (short)f2bf(a.x); o[1] = (short)f2bf(a.y);
  o[2] = (short)f2bf(a.z); o[3] = (short)f2bf(a.w);
  o[4] = (short)f2bf(b.x); o[5] = (short)f2bf(b.y);
  o[6] = (short)f2bf(b.z); o[7] = (short)f2bf(b.w);
  *(short8*)(dst + (size_t)k * 8) = o;
}

// K2: usum half-partials. block = n*16 + bt*2 + h (256 blocks, 16 waves).
// wave w owns c in [h*512 + w*32, +32) -> 2 independent 8-step K=32 chains.
// LDS-reduce 16 waves -> usum2[h][n][b][d].
__global__ __launch_bounds__(1024) void k_usum(const ushort_t* __restrict__ xb,
                                               const ushort_t* __restrict__ Wb,
                                               float* __restrict__ usum2) {
  __shared__ f32x4 red[16][64];  // 16 KB
  int bx = blockIdx.x;
  int n = bx >> 4, bt = (bx >> 1) & 7, h = bx & 1;
  int w = threadIdx.x >> 6, l = threadIdx.x & 63;
  int q = l >> 4, b16 = l & 15;
  int c0 = h * 512 + w * 32;
  const ushort_t* ap0 = Wb + (((size_t)(n * NC + c0 + (q >> 1)) * ND + b16) * NI) + (q & 1) * 8;
  const ushort_t* bp0 = xb + (size_t)(bt * 16 + b16) * (NC * NI) + (c0 + (q >> 1)) * NI + (q & 1) * 8;
  const ushort_t* ap1 = ap0 + 16 * ND * NI;  // +16 c
  const ushort_t* bp1 = bp0 + 16 * NI;
  f32x4 acc0 = {0.f, 0.f, 0.f, 0.f};
  f32x4 acc1 = {0.f, 0.f, 0.f, 0.f};
#pragma unroll
  for (int s = 0; s < 8; ++s) {
    short8 a0 = *(const short8*)ap0;
    short8 b0 = *(const short8*)bp0;
    short8 a1 = *(const short8*)ap1;
    short8 b1 = *(const short8*)bp1;
    acc0 = __builtin_amdgcn_mfma_f32_16x16x32_bf16(a0, b0, acc0, 0, 0, 0);
    acc1 = __builtin_amdgcn_mfma_f32_16x16x32_bf16(a1, b1, acc1, 0, 0, 0);
    ap0 += 2 * ND * NI; bp0 += 2 * NI;
    ap1 += 2 * ND * NI; bp1 += 2 * NI;
  }
  red[w][l] = acc0 + acc1;
  __syncthreads();
  if (threadIdx.x < 64) {
    f32x4 t = red[0][l];
#pragma unroll
    for (int k = 1; k < 16; ++k) t += red[k][l];
    *(f32x4*)(usum2 + (((size_t)h * NN + n) * NB + bt * 16 + b16) * ND + q * 4) = t;
  }
}

// K3: fused scores + softmax + weighted-sum, u_hat tiles held in REGISTERS.
// grid = 1024 blocks (bt = bx>>7, cc = bx&127, c_blk = 8), 512 threads = 8 waves.
// Wave w handles n = w and n = w+8. W and x are read once per block.
__global__ __launch_bounds__(512, 4) void k_bc(const ushort_t* __restrict__ xb,
                                               const ushort_t* __restrict__ Wb,
                                               const float* __restrict__ usum2,
                                               const float* __restrict__ Bbias,
                                               float* __restrict__ part) {
  __shared__ float scl[NN][8][16];  // [n][c][b16], 8 KB
  int bx = blockIdx.x;
  int bt = bx >> 7, cc = bx & 127;
  int w = threadIdx.x >> 6, l = threadIdx.x & 63;
  int q = l >> 4, b16 = l & 15;
  int c0 = cc * 8;
  int n0 = w, n1 = w + 8;

  // usum (sum of halves) for n0, n1
  const float* u0p = usum2 + ((size_t)n0 * NB + bt * 16 + b16) * ND + q * 4;
  f32x4 us0 = *(const f32x4*)u0p + *(const f32x4*)(u0p + (size_t)NN * NB * ND);
  const float* u1p = usum2 + ((size_t)n1 * NB + bt * 16 + b16) * ND + q * 4;
  f32x4 us1 = *(const f32x4*)u1p + *(const f32x4*)(u1p + (size_t)NN * NB * ND);

  const ushort_t* bp = xb + (size_t)(bt * 16 + b16) * (NC * NI) + c0 * NI + (q & 1) * 8;
  const ushort_t* ap0 = Wb + (((size_t)(n0 * NC + c0) * ND + b16) * NI) + (q & 1) * 8;
  const ushort_t* ap1 = Wb + (((size_t)(n1 * NC + c0) * ND + b16) * NI) + (q & 1) * 8;

  f32x4 t0[8], t1[8];  // u_hat d-tiles, kept in registers across softmax

  // phase 1a: n0 — u_hat tiles + scores
#pragma unroll 4
  for (int c = 0; c < 8; ++c) {
    short8 av = {0, 0, 0, 0, 0, 0, 0, 0};
    short8 bv = {0, 0, 0, 0, 0, 0, 0, 0};
    if (q < 2) {
      av = *(const short8*)(ap0 + c * (ND * NI));
      bv = *(const short8*)(bp + c * NI);
    }
    f32x4 z = {0.f, 0.f, 0.f, 0.f};
    f32x4 d = __builtin_amdgcn_mfma_f32_16x16x32_bf16(av, bv, z, 0, 0, 0);
    t0[c] = d;
    float v = us0[0] * d[0] + us0[1] * d[1] + us0[2] * d[2] + us0[3] * d[3];
    v += __shfl_xor(v, 16);
    v += __shfl_xor(v, 32);
    if (l < 16) scl[n0][c][l] = COEF * v;
  }
  // phase 1b: n1
#pragma unroll 4
  for (int c = 0; c < 8; ++c) {
    short8 av = {0, 0, 0, 0, 0, 0, 0, 0};
    short8 bv = {0, 0, 0, 0, 0, 0, 0, 0};
    if (q < 2) {
      av = *(const short8*)(ap1 + c * (ND * NI));
      bv = *(const short8*)(bp + c * NI);
    }
    f32x4 z = {0.f, 0.f, 0.f, 0.f};
    f32x4 d = __builtin_amdgcn_mfma_f32_16x16x32_bf16(av, bv, z, 0, 0, 0);
    t1[c] = d;
    float v = us1[0] * d[0] + us1[1] * d[1] + us1[2] * d[2] + us1[3] * d[3];
    v += __shfl_xor(v, 16);
    v += __shfl_xor(v, 32);
    if (l < 16) scl[n1][c][l] = COEF * v;
  }
  __syncthreads();

  // phase 2: softmax over n + bias (threads < 128; thread owns (c,b) column)
  if (threadIdx.x < 128) {
    int c = threadIdx.x >> 4, b = threadIdx.x & 15;
    float v[NN];
    float m = -1e30f;
#pragma unroll
    for (int k = 0; k < NN; ++k) {
      v[k] = scl[k][c][b];
      m = fmaxf(m, v[k]);
    }
    float sum = 0.f;
#pragma unroll
    for (int k = 0; k < NN; ++k) {
      v[k] = expf(v[k] - m);
      sum += v[k];
    }
    float inv = 1.0f / sum;
#pragma unroll
    for (int k = 0; k < NN; ++k) {
      scl[k][c][b] = v[k] * inv + Bbias[k * NC + c0 + c];
    }
  }
  __syncthreads();

  // phase 3: weighted sum from register tiles
  f32x4 acc0 = {0.f, 0.f, 0.f, 0.f};
  f32x4 acc1 = {0.f, 0.f, 0.f, 0.f};
#pragma unroll
  for (int c = 0; c < 8; ++c) {
    float cf0 = scl[n0][c][b16];
    float cf1 = scl[n1][c][b16];
    acc0[0] = fmaf(cf0, t0[c][0], acc0[0]);
    acc0[1] = fmaf(cf0, t0[c][1], acc0[1]);
    acc0[2] = fmaf(cf0, t0[c][2], acc0[2]);
    acc0[3] = fmaf(cf0, t0[c][3], acc0[3]);
    acc1[0] = fmaf(cf1, t1[c][0], acc1[0]);
    acc1[1] = fmaf(cf1, t1[c][1], acc1[1]);
    acc1[2] = fmaf(cf1, t1[c][2], acc1[2]);
    acc1[3] = fmaf(cf1, t1[c][3], acc1[3]);
  }
  *(f32x4*)(part + ((size_t)((n0 * 8 + bt) * 128 + cc)) * 256 + b16 * 16 + q * 4) = acc0;
  *(f32x4*)(part + ((size_t)((n1 * 8 + bt) * 128 + cc)) * 256 + b16 * 16 + q * 4) = acc1;
}

// K4: reduce s partials over 128 cc (2-way split) + squash -> out[b][n][d].
__global__ __launch_bounds__(256) void k_fin(const float* __restrict__ part,
                                             float* __restrict__ out) {
  int id2 = blockIdx.x * 256 + threadIdx.x;  // 16384
  int h = id2 & 1;
  int id = id2 >> 1;  // 8192 = b*64 + n*4 + dq
  int dq = id & 3, n = (id >> 2) & 15, b = id >> 6;
  int bt = b >> 4, b16 = b & 15;
  f32x4 sv = {0.f, 0.f, 0.f, 0.f};
  const float* pp = part + ((size_t)((n * 8 + bt) * 128 + h * 64)) * 256 + b16 * 16 + dq * 4;
  for (int k = 0; k < 64; ++k) {
    sv += *(const f32x4*)pp;
    pp += 256;
  }
  // combine h halves (adjacent lanes)
  sv[0] += __shfl_xor(sv[0], 1);
  sv[1] += __shfl_xor(sv[1], 1);
  sv[2] += __shfl_xor(sv[2], 1);
  sv[3] += __shfl_xor(sv[3], 1);
  float sq = sv[0] * sv[0] + sv[1] * sv[1] + sv[2] * sv[2] + sv[3] * sv[3];
  sq += __shfl_xor(sq, 2);
  sq += __shfl_xor(sq, 4);
  float norm = sqrtf(sq);
  float scale = (1.0f - expf(-norm)) / sqrtf(sq + 1e-8f);
  if (h == 0) {
    f32x4 o = {sv[0] * scale, sv[1] * scale, sv[2] * scale, sv[3] * scale};
    *(f32x4*)(out + (size_t)id * 4) = o;
  }
}

extern "C" void kernel_launch(void* const* d_in, const int* in_sizes, int n_in,
                              void* d_out, int out_size, void* d_ws, size_t ws_size,
                              hipStream_t stream) {
  const float* x = (const float*)d_in[0];   // [128][1024][16]
  const float* W = (const float*)d_in[1];   // [1][16][1024][16][16]
  const float* Bb = (const float*)d_in[2];  // [16][1][1024]
  float* out = (float*)d_out;               // [128][16][16]
  float* ws = (float*)d_ws;

  // ws layout (float units): ~29.6 MB total (ws is ~268 MB)
  ushort_t* xb = (ushort_t*)ws;              // 2,097,152 bf16 = 1,048,576 f
  ushort_t* Wb = (ushort_t*)(ws + 1048576);  // 4,194,304 bf16 = 2,097,152 f
  float* part = ws + 1048576 + 2097152;      // [16][8][128][256] = 4,194,304 f
  float* usum2 = part + 4194304;             // [2][16][128][16] = 65,536 f

  hipLaunchKernelGGL(k_prep, dim3(3072), dim3(256), 0, stream,
                     (const float4*)x, (const float4*)W, xb, Wb);
  hipLaunchKernelGGL(k_usum, dim3(256), dim3(1024), 0, stream, xb, Wb, usum2);
  hipLaunchKernelGGL(k_bc, dim3(1024), dim3(512), 0, stream, xb, Wb, usum2, Bb, part);
  hipLaunchKernelGGL(k_fin, dim3(64), dim3(256), 0, stream, part, out);
}

// Round 7
// 48.311 us; speedup vs baseline: 1.8846x; 1.4617x over previous
//
#include <hip/hip_runtime.h>
#include <math.h>

// DigitCaps2: B=128, C=1024 in_caps, I=16 in_dim, N=16 num_caps, D=16 dim_caps
#define NB 128
#define NC 1024
#define NN 16
#define ND 16
#define NI 16
#define COEF 0.25f

typedef __attribute__((ext_vector_type(8))) short short8;
typedef __attribute__((ext_vector_type(4))) float f32x4;
typedef unsigned short ushort_t;

__device__ __forceinline__ unsigned short f2bf(float f) {
  unsigned int u = __builtin_bit_cast(unsigned int, f);
  u += 0x7fffu + ((u >> 16) & 1u);
  return (unsigned short)(u >> 16);
}

// K1: convert x (262144 groups of 8) and W (524288 groups) to bf16.
__global__ __launch_bounds__(256) void k_prep(const float4* __restrict__ x,
                                              const float4* __restrict__ W,
                                              ushort_t* __restrict__ xb,
                                              ushort_t* __restrict__ Wb) {
  int id = blockIdx.x * 256 + threadIdx.x;
  const float4* src;
  ushort_t* dst;
  int k;
  if (id < 262144) { src = x; dst = xb; k = id; }
  else { src = W; dst = Wb; k = id - 262144; }
  float4 a = src[2 * k], b = src[2 * k + 1];
  short8 o;
  o[0] = (short)f2bf(a.x); o[1] = (short)f2bf(a.y);
  o[2] = (short)f2bf(a.z); o[3] = (short)f2bf(a.w);
  o[4] = (short)f2bf(b.x); o[5] = (short)f2bf(b.y);
  o[6] = (short)f2bf(b.z); o[7] = (short)f2bf(b.w);
  *(short8*)(dst + (size_t)k * 8) = o;
}

// K2: usum half-partials. block = n*16 + bt*2 + h (256 blocks, 16 waves).
// wave w owns c in [h*512 + w*32, +32) -> 2 independent 8-step K=32 chains.
// LDS-reduce 16 waves -> usum2[h][n][b][d].
__global__ __launch_bounds__(1024) void k_usum(const ushort_t* __restrict__ xb,
                                               const ushort_t* __restrict__ Wb,
                                               float* __restrict__ usum2) {
  __shared__ f32x4 red[16][64];  // 16 KB
  int bx = blockIdx.x;
  int n = bx >> 4, bt = (bx >> 1) & 7, h = bx & 1;
  int w = threadIdx.x >> 6, l = threadIdx.x & 63;
  int q = l >> 4, b16 = l & 15;
  int c0 = h * 512 + w * 32;
  const ushort_t* ap0 = Wb + (((size_t)(n * NC + c0 + (q >> 1)) * ND + b16) * NI) + (q & 1) * 8;
  const ushort_t* bp0 = xb + (size_t)(bt * 16 + b16) * (NC * NI) + (c0 + (q >> 1)) * NI + (q & 1) * 8;
  const ushort_t* ap1 = ap0 + 16 * ND * NI;  // +16 c
  const ushort_t* bp1 = bp0 + 16 * NI;
  f32x4 acc0 = {0.f, 0.f, 0.f, 0.f};
  f32x4 acc1 = {0.f, 0.f, 0.f, 0.f};
#pragma unroll
  for (int s = 0; s < 8; ++s) {
    short8 a0 = *(const short8*)ap0;
    short8 b0 = *(const short8*)bp0;
    short8 a1 = *(const short8*)ap1;
    short8 b1 = *(const short8*)bp1;
    acc0 = __builtin_amdgcn_mfma_f32_16x16x32_bf16(a0, b0, acc0, 0, 0, 0);
    acc1 = __builtin_amdgcn_mfma_f32_16x16x32_bf16(a1, b1, acc1, 0, 0, 0);
    ap0 += 2 * ND * NI; bp0 += 2 * NI;
    ap1 += 2 * ND * NI; bp1 += 2 * NI;
  }
  red[w][l] = acc0 + acc1;
  __syncthreads();
  if (threadIdx.x < 64) {
    f32x4 t = red[0][l];
#pragma unroll
    for (int k = 1; k < 16; ++k) t += red[k][l];
    *(f32x4*)(usum2 + (((size_t)h * NN + n) * NB + bt * 16 + b16) * ND + q * 4) = t;
  }
}

// K3: fused scores + softmax + weighted-sum. LDS-staged W/x, register u_hat tiles.
// grid = 1024 blocks (bt = bx>>7, cc = bx&127, c_blk = 8), 512 threads = 8 waves.
// Wave w handles n = w and n = w+8. W/x read from global ONCE per block (dense).
__global__ __launch_bounds__(512, 4) void k_bc(const ushort_t* __restrict__ xb,
                                               const ushort_t* __restrict__ Wb,
                                               const float* __restrict__ usum2,
                                               const float* __restrict__ Bbias,
                                               float* __restrict__ part) {
  __shared__ ushort_t Wl[NN][8][ND][NI];  // 64 KB, [n][c][d][i]
  __shared__ ushort_t xl[16][136];        // x tile [b][c*16+i], padded stride
  __shared__ float scl[NN][8][16];        // 8 KB, [n][c][b16]
  int bx = blockIdx.x;
  int bt = bx >> 7, cc = bx & 127;
  int t = threadIdx.x;
  int w = t >> 6, l = t & 63;
  int q = l >> 4, b16 = l & 15;
  int c0 = cc * 8;
  int n0 = w, n1 = w + 8;

  // ---- stage W slice: 16 n x (8 c x 256) shorts = 4096 short8 groups ----
  {
    ushort_t* Wflat = &Wl[0][0][0][0];
    const ushort_t* Wsrc = Wb + (size_t)c0 * (ND * NI);
#pragma unroll
    for (int r = 0; r < 8; ++r) {
      int g = r * 512 + t;          // 0..4095
      int n = g >> 8, rem = g & 255;  // 256 short8 per n-chunk (contiguous)
      *(short8*)(Wflat + n * 2048 + rem * 8) =
          *(const short8*)(Wsrc + (size_t)n * (NC * ND * NI) + rem * 8);
    }
    // stage x slice: 16 b x 8 c x 16 i
    if (t < 256) {
      int b = t >> 4, j = t & 15;  // j = c*2 + i-half
      int c = j >> 1, i8 = j & 1;
      *(short8*)(&xl[b][c * 16 + i8 * 8]) =
          *(const short8*)(xb + ((size_t)(bt * 16 + b) * NC + c0 + c) * NI + i8 * 8);
    }
  }

  // usum (sum of halves) for n0, n1 (overlaps with staging)
  const float* u0p = usum2 + ((size_t)n0 * NB + bt * 16 + b16) * ND + q * 4;
  f32x4 us0 = *(const f32x4*)u0p + *(const f32x4*)(u0p + (size_t)NN * NB * ND);
  const float* u1p = usum2 + ((size_t)n1 * NB + bt * 16 + b16) * ND + q * 4;
  f32x4 us1 = *(const f32x4*)u1p + *(const f32x4*)(u1p + (size_t)NN * NB * ND);

  __syncthreads();

  f32x4 t0[8], t1[8];  // u_hat d-tiles, kept in registers across softmax

  // phase 1a: n0 — u_hat tiles + scores (all operands from LDS)
#pragma unroll
  for (int c = 0; c < 8; ++c) {
    short8 av = {0, 0, 0, 0, 0, 0, 0, 0};
    short8 bv = {0, 0, 0, 0, 0, 0, 0, 0};
    if (q < 2) {
      av = *(const short8*)(&Wl[n0][c][b16][q * 8]);
      bv = *(const short8*)(&xl[b16][c * 16 + q * 8]);
    }
    f32x4 z = {0.f, 0.f, 0.f, 0.f};
    f32x4 d = __builtin_amdgcn_mfma_f32_16x16x32_bf16(av, bv, z, 0, 0, 0);
    t0[c] = d;
    float v = us0[0] * d[0] + us0[1] * d[1] + us0[2] * d[2] + us0[3] * d[3];
    v += __shfl_xor(v, 16);
    v += __shfl_xor(v, 32);
    if (l < 16) scl[n0][c][l] = COEF * v;
  }
  // phase 1b: n1
#pragma unroll
  for (int c = 0; c < 8; ++c) {
    short8 av = {0, 0, 0, 0, 0, 0, 0, 0};
    short8 bv = {0, 0, 0, 0, 0, 0, 0, 0};
    if (q < 2) {
      av = *(const short8*)(&Wl[n1][c][b16][q * 8]);
      bv = *(const short8*)(&xl[b16][c * 16 + q * 8]);
    }
    f32x4 z = {0.f, 0.f, 0.f, 0.f};
    f32x4 d = __builtin_amdgcn_mfma_f32_16x16x32_bf16(av, bv, z, 0, 0, 0);
    t1[c] = d;
    float v = us1[0] * d[0] + us1[1] * d[1] + us1[2] * d[2] + us1[3] * d[3];
    v += __shfl_xor(v, 16);
    v += __shfl_xor(v, 32);
    if (l < 16) scl[n1][c][l] = COEF * v;
  }
  __syncthreads();

  // phase 2: softmax over n + bias (threads < 128; thread owns (c,b) column)
  if (t < 128) {
    int c = t >> 4, b = t & 15;
    float v[NN];
    float m = -1e30f;
#pragma unroll
    for (int k = 0; k < NN; ++k) {
      v[k] = scl[k][c][b];
      m = fmaxf(m, v[k]);
    }
    float sum = 0.f;
#pragma unroll
    for (int k = 0; k < NN; ++k) {
      v[k] = expf(v[k] - m);
      sum += v[k];
    }
    float inv = 1.0f / sum;
#pragma unroll
    for (int k = 0; k < NN; ++k) {
      scl[k][c][b] = v[k] * inv + Bbias[k * NC + c0 + c];
    }
  }
  __syncthreads();

  // phase 3: weighted sum from register tiles
  f32x4 acc0 = {0.f, 0.f, 0.f, 0.f};
  f32x4 acc1 = {0.f, 0.f, 0.f, 0.f};
#pragma unroll
  for (int c = 0; c < 8; ++c) {
    float cf0 = scl[n0][c][b16];
    float cf1 = scl[n1][c][b16];
    acc0[0] = fmaf(cf0, t0[c][0], acc0[0]);
    acc0[1] = fmaf(cf0, t0[c][1], acc0[1]);
    acc0[2] = fmaf(cf0, t0[c][2], acc0[2]);
    acc0[3] = fmaf(cf0, t0[c][3], acc0[3]);
    acc1[0] = fmaf(cf1, t1[c][0], acc1[0]);
    acc1[1] = fmaf(cf1, t1[c][1], acc1[1]);
    acc1[2] = fmaf(cf1, t1[c][2], acc1[2]);
    acc1[3] = fmaf(cf1, t1[c][3], acc1[3]);
  }
  *(f32x4*)(part + ((size_t)((n0 * 8 + bt) * 128 + cc)) * 256 + b16 * 16 + q * 4) = acc0;
  *(f32x4*)(part + ((size_t)((n1 * 8 + bt) * 128 + cc)) * 256 + b16 * 16 + q * 4) = acc1;
}

// K4: reduce s partials over 128 cc (2-way split) + squash -> out[b][n][d].
__global__ __launch_bounds__(256) void k_fin(const float* __restrict__ part,
                                             float* __restrict__ out) {
  int id2 = blockIdx.x * 256 + threadIdx.x;  // 16384
  int h = id2 & 1;
  int id = id2 >> 1;  // 8192 = b*64 + n*4 + dq
  int dq = id & 3, n = (id >> 2) & 15, b = id >> 6;
  int bt = b >> 4, b16 = b & 15;
  f32x4 sv = {0.f, 0.f, 0.f, 0.f};
  const float* pp = part + ((size_t)((n * 8 + bt) * 128 + h * 64)) * 256 + b16 * 16 + dq * 4;
  for (int k = 0; k < 64; ++k) {
    sv += *(const f32x4*)pp;
    pp += 256;
  }
  // combine h halves (adjacent lanes)
  sv[0] += __shfl_xor(sv[0], 1);
  sv[1] += __shfl_xor(sv[1], 1);
  sv[2] += __shfl_xor(sv[2], 1);
  sv[3] += __shfl_xor(sv[3], 1);
  float sq = sv[0] * sv[0] + sv[1] * sv[1] + sv[2] * sv[2] + sv[3] * sv[3];
  sq += __shfl_xor(sq, 2);
  sq += __shfl_xor(sq, 4);
  float norm = sqrtf(sq);
  float scale = (1.0f - expf(-norm)) / sqrtf(sq + 1e-8f);
  if (h == 0) {
    f32x4 o = {sv[0] * scale, sv[1] * scale, sv[2] * scale, sv[3] * scale};
    *(f32x4*)(out + (size_t)id * 4) = o;
  }
}

extern "C" void kernel_launch(void* const* d_in, const int* in_sizes, int n_in,
                              void* d_out, int out_size, void* d_ws, size_t ws_size,
                              hipStream_t stream) {
  const float* x = (const float*)d_in[0];   // [128][1024][16]
  const float* W = (const float*)d_in[1];   // [1][16][1024][16][16]
  const float* Bb = (const float*)d_in[2];  // [16][1][1024]
  float* out = (float*)d_out;               // [128][16][16]
  float* ws = (float*)d_ws;

  // ws layout (float units): ~29.6 MB total
  ushort_t* xb = (ushort_t*)ws;              // 2,097,152 bf16 = 1,048,576 f
  ushort_t* Wb = (ushort_t*)(ws + 1048576);  // 4,194,304 bf16 = 2,097,152 f
  float* part = ws + 1048576 + 2097152;      // [16][8][128][256] = 4,194,304 f
  float* usum2 = part + 4194304;             // [2][16][128][16] = 65,536 f

  hipLaunchKernelGGL(k_prep, dim3(3072), dim3(256), 0, stream,
                     (const float4*)x, (const float4*)W, xb, Wb);
  hipLaunchKernelGGL(k_usum, dim3(256), dim3(1024), 0, stream, xb, Wb, usum2);
  hipLaunchKernelGGL(k_bc, dim3(1024), dim3(512), 0, stream, xb, Wb, usum2, Bb, part);
  hipLaunchKernelGGL(k_fin, dim3(64), dim3(256), 0, stream, part, out);
}